// Round 3
// baseline (197.562 us; speedup 1.0000x reference)
//
#include <hip/hip_runtime.h>

// Problem: B=32, GS=1024, PARAM=64, KEEPCONST=16, ITERATIONS=10, K_DIV=16.
// All tensors FLOAT32. Closed form of the 10-iteration shift recurrence:
//   out[row, j] = f^q(val[row, j&15]),  q = j>>4,  f(x) = clip(x*s, -1, 1),
//   s = sum(mat[row, :]) / 16.
//
// R2: one wave per row was latency-bound (4 loads in flight, then a serial
// shuffle chain). Now 4 rows per wave: 16 independent dwordx4 loads issued
// back-to-back, 4 interleaved butterfly reductions. 256 B/lane in flight.

__global__ __launch_bounds__(256) void gltrivmlp_kernel(
    const float* __restrict__ mat,   // [nrows, 1024] f32
    const float* __restrict__ val,   // [nrows, 64]   f32
    float* __restrict__ out,         // [nrows, 64]   f32
    int nrows)
{
    const int wave_in_block = (int)(threadIdx.x >> 6);
    const int lane          = (int)(threadIdx.x & 63u);
    // 4 waves per block, 4 rows per wave -> 16 rows per block
    const int base_row = (int)(blockIdx.x * 16u) + wave_in_block * 4;
    if (base_row >= nrows) return;

    const float* rp = mat + (size_t)base_row * 1024;

    // ---- 16 independent coalesced float4 loads (4 rows x 4 segments) ----
    float4 v[4][4];
#pragma unroll
    for (int r = 0; r < 4; ++r)
#pragma unroll
        for (int h = 0; h < 4; ++h)
            v[r][h] = *(const float4*)(rp + r * 1024 + h * 256 + lane * 4);

    // ---- per-lane partial sums (16 floats per row per lane) ----
    float s[4];
#pragma unroll
    for (int r = 0; r < 4; ++r) {
        float a0 = v[r][0].x + v[r][0].y + v[r][0].z + v[r][0].w;
        float a1 = v[r][1].x + v[r][1].y + v[r][1].z + v[r][1].w;
        float a2 = v[r][2].x + v[r][2].y + v[r][2].z + v[r][2].w;
        float a3 = v[r][3].x + v[r][3].y + v[r][3].z + v[r][3].w;
        s[r] = (a0 + a1) + (a2 + a3);
    }

    // ---- 4 interleaved 64-lane butterfly reductions ----
#pragma unroll
    for (int off = 32; off >= 1; off >>= 1)
#pragma unroll
        for (int r = 0; r < 4; ++r)
            s[r] += __shfl_xor(s[r], off, 64);

    // ---- epilogue: lane j emits column j of each of the 4 rows ----
    const int q = lane >> 4;
#pragma unroll
    for (int r = 0; r < 4; ++r) {
        const float sc = s[r] * (1.0f / 16.0f);
        float x = val[(size_t)(base_row + r) * 64 + (lane & 15)];
        if (q >= 1) x = fminf(fmaxf(x * sc, -1.f), 1.f);
        if (q >= 2) x = fminf(fmaxf(x * sc, -1.f), 1.f);
        if (q >= 3) x = fminf(fmaxf(x * sc, -1.f), 1.f);
        out[(size_t)(base_row + r) * 64 + lane] = x;
    }
}

extern "C" void kernel_launch(void* const* d_in, const int* in_sizes, int n_in,
                              void* d_out, int out_size, void* d_ws, size_t ws_size,
                              hipStream_t stream) {
    (void)n_in; (void)d_ws; (void)ws_size; (void)out_size;
    const float* mat = (const float*)d_in[0];
    const float* val = (const float*)d_in[1];
    float* out = (float*)d_out;

    const int nrows = in_sizes[0] / 1024;              // 32768 rows
    const int rows_per_block = 16;                     // 4 waves x 4 rows
    const int grid = (nrows + rows_per_block - 1) / rows_per_block;

    gltrivmlp_kernel<<<grid, 256, 0, stream>>>(mat, val, out, nrows);
}

// Round 4
// 193.632 us; speedup vs baseline: 1.0203x; 1.0203x over previous
//
#include <hip/hip_runtime.h>

// Problem: B=32, GS=1024, PARAM=64, KEEPCONST=16, ITERATIONS=10, K_DIV=16.
// All tensors FLOAT32. Closed form of the 10-iteration shift recurrence:
//   out[row, j] = f^q(val[row, j&15]),  q = j>>4,  f(x) = clip(x*s, -1, 1),
//   s = sum(mat[row, :]) / 16.
//
// R4: persistent uniform grid (1024 blocks, all co-resident) + register
// double-buffered pipeline. Each wave owns 8 consecutive rows, processes 2 at
// a time, and issues the next 2 rows' 8 dwordx4 loads BEFORE reducing the
// current pair -> memory issue is continuous, no block-generation bubbles,
// no tail. VGPR ~96 (2 x 32 data regs) -> 5 waves/SIMD.

__device__ __forceinline__ void load2(float4 (&buf)[2][4],
                                      const float* __restrict__ p, int lane) {
#pragma unroll
    for (int r = 0; r < 2; ++r)
#pragma unroll
        for (int h = 0; h < 4; ++h)
            buf[r][h] = *(const float4*)(p + r * 1024 + h * 256 + lane * 4);
}

__device__ __forceinline__ void process2(const float4 (&buf)[2][4],
                                         const float* __restrict__ val,
                                         float* __restrict__ out,
                                         int row, int lane) {
    float s[2];
#pragma unroll
    for (int r = 0; r < 2; ++r) {
        float a0 = buf[r][0].x + buf[r][0].y + buf[r][0].z + buf[r][0].w;
        float a1 = buf[r][1].x + buf[r][1].y + buf[r][1].z + buf[r][1].w;
        float a2 = buf[r][2].x + buf[r][2].y + buf[r][2].z + buf[r][2].w;
        float a3 = buf[r][3].x + buf[r][3].y + buf[r][3].z + buf[r][3].w;
        s[r] = (a0 + a1) + (a2 + a3);
    }
    // two interleaved 64-lane butterfly reductions
#pragma unroll
    for (int off = 32; off >= 1; off >>= 1)
#pragma unroll
        for (int r = 0; r < 2; ++r)
            s[r] += __shfl_xor(s[r], off, 64);

    const int q = lane >> 4;
#pragma unroll
    for (int r = 0; r < 2; ++r) {
        const float sc = s[r] * (1.0f / 16.0f);
        float x = val[(size_t)(row + r) * 64 + (lane & 15)];
        if (q >= 1) x = fminf(fmaxf(x * sc, -1.f), 1.f);
        if (q >= 2) x = fminf(fmaxf(x * sc, -1.f), 1.f);
        if (q >= 3) x = fminf(fmaxf(x * sc, -1.f), 1.f);
        out[(size_t)(row + r) * 64 + lane] = x;
    }
}

__global__ __launch_bounds__(256) void gltrivmlp_kernel(
    const float* __restrict__ mat,   // [nrows, 1024] f32
    const float* __restrict__ val,   // [nrows, 64]   f32
    float* __restrict__ out,         // [nrows, 64]   f32
    int nrows)
{
    const int wave = (int)(blockIdx.x * 4u) + (int)(threadIdx.x >> 6);
    const int lane = (int)(threadIdx.x & 63u);
    const int row0 = wave * 8;                 // 8 consecutive rows per wave
    if (row0 >= nrows) return;

    const float* rp = mat + (size_t)row0 * 1024;

    float4 A[2][4], B[2][4];
    // pipeline: 2-deep prefetch, then reduce/load alternation (ping-pong)
    load2(A, rp,            lane);             // rows 0,1
    load2(B, rp + 2 * 1024, lane);             // rows 2,3
    process2(A, val, out, row0 + 0, lane);
    load2(A, rp + 4 * 1024, lane);             // rows 4,5
    process2(B, val, out, row0 + 2, lane);
    load2(B, rp + 6 * 1024, lane);             // rows 6,7
    process2(A, val, out, row0 + 4, lane);
    process2(B, val, out, row0 + 6, lane);
}

extern "C" void kernel_launch(void* const* d_in, const int* in_sizes, int n_in,
                              void* d_out, int out_size, void* d_ws, size_t ws_size,
                              hipStream_t stream) {
    (void)n_in; (void)d_ws; (void)ws_size; (void)out_size;
    const float* mat = (const float*)d_in[0];
    const float* val = (const float*)d_in[1];
    float* out = (float*)d_out;

    const int nrows = in_sizes[0] / 1024;      // 32768 rows
    const int rows_per_block = 4 * 8;          // 4 waves x 8 rows
    const int grid = (nrows + rows_per_block - 1) / rows_per_block;  // 1024

    gltrivmlp_kernel<<<grid, 256, 0, stream>>>(mat, val, out, nrows);
}